// Round 6
// baseline (376.081 us; speedup 1.0000x reference)
//
#include <hip/hip_runtime.h>
#include <stdint.h>

typedef unsigned short u16;
typedef __bf16 bf16x8 __attribute__((ext_vector_type(8)));
typedef float  f32x4  __attribute__((ext_vector_type(4)));
typedef float  f32x16 __attribute__((ext_vector_type(16)));
typedef unsigned int u32x4 __attribute__((ext_vector_type(4)));

#define MFMA16(a,b,c) __builtin_amdgcn_mfma_f32_16x16x32_bf16((a),(b),(c),0,0,0)
#define MFMA32(a,b,c) __builtin_amdgcn_mfma_f32_32x32x16_bf16((a),(b),(c),0,0,0)

#if __has_builtin(__builtin_amdgcn_exp2f)
#define EXP2F(x) __builtin_amdgcn_exp2f(x)
#else
#define EXP2F(x) exp2f(x)
#endif

// B=32, N=512, C=1024, H=16, HD=64; SCALE = 1/8
__device__ __forceinline__ u16 f2b(float f) {
  unsigned int u = __builtin_bit_cast(unsigned int, f);
  u += 0x7fffu + ((u >> 16) & 1u);
  return (u16)(u >> 16);
}

// async 16B global->LDS (lds dest wave-uniform; lane i lands at l + i*16)
__device__ __forceinline__ void gll16(const u16* g, u16* l) {
  __builtin_amdgcn_global_load_lds((const __attribute__((address_space(1))) unsigned int*)g,
                                   (__attribute__((address_space(3))) unsigned int*)l,
                                   16, 0, 0);
}

// packed f32x2 -> bf16x2
__device__ __forceinline__ unsigned cvtpk(float lo, float hi) {
  unsigned r;
  asm("v_cvt_pk_bf16_f32 %0, %1, %2" : "=v"(r) : "v"(lo), "v"(hi));
  return r;
}
// swap upper 32 lanes of x with lower 32 lanes of y
__device__ __forceinline__ void pl32swap(unsigned &x, unsigned &y) {
  asm volatile("v_permlane32_swap_b32 %0, %1" : "+v"(x), "+v"(y));
}

#define BARR() __builtin_amdgcn_s_barrier()
#define SCHED0() __builtin_amdgcn_sched_barrier(0)
#define LGKM(N) do { asm volatile("s_waitcnt lgkmcnt(" #N ")" ::: "memory"); __builtin_amdgcn_sched_barrier(0); } while (0)
#define VMC(N) do { asm volatile("s_waitcnt vmcnt(" #N ")" ::: "memory"); __builtin_amdgcn_sched_barrier(0); } while (0)
#define PRIO1() __builtin_amdgcn_s_setprio(1)
#define PRIO0() __builtin_amdgcn_s_setprio(0)

// ------------------------------------------------------------------
// cvt_all: fp32 -> bf16 for x (16.78M), W_qkv (3.15M), W_proj (1.05M)
// ------------------------------------------------------------------
__global__ __launch_bounds__(256)
void cvt_all(const float* __restrict__ X, const float* __restrict__ Wq,
             const float* __restrict__ Wp, u16* __restrict__ Xb,
             u16* __restrict__ Wqb, u16* __restrict__ Wpb)
{
  size_t i = (size_t)blockIdx.x * 256 + threadIdx.x;   // float4 index
  const float* src; u16* dst; size_t off;
  if (i < 4194304)       { src = X;  dst = Xb;  off = i; }
  else if (i < 4980736)  { src = Wq; dst = Wqb; off = i - 4194304; }
  else                   { src = Wp; dst = Wpb; off = i - 4980736; }
  float4 v = ((const float4*)src)[off];
  uint2 p;
  p.x = f2b(v.x) | ((unsigned)f2b(v.y) << 16);
  p.y = f2b(v.z) | ((unsigned)f2b(v.w) << 16);
  ((uint2*)dst)[off] = p;
}

// ------------------------------------------------------------------
// gemm8p: 256x256 tile, BK=64, 8 waves (2Mx4N), counted-lgkm schedule,
// DEEP PREFETCH (round 6): A triple-buffered (3x32KB), B double (2x32KB)
// = 160KB LDS. A staged 2 tiles ahead at iter top (3rd buffer -> no WAR
// hazard); B staged 2 ahead after BARR1 (all B-reads sealed by lgkm(8)
// + barrier). ENDW vmcnt(8): outstanding = A(T+2)4+B(T+2)4 (+older);
// waiting to <=8 forces A(T+1),B(T+1) landed. Latency deadline for A
// is now ~2 iterations (was ~1); avg in-flight 12 loads/wave (was 8).
// Buffer cycle: CURA = T%3, CURB = T&1 -> 6-tile macro pattern x2 +
// 4 explicit tail tiles (vmcnt(0) at T=14).
// Grid mapping: row-major XCD-chunked (round-3 proven best; round-5's
// column-major doubled FETCH_SIZE and regressed).
// ------------------------------------------------------------------
#define DS_A(CUR, AF, RBASE) do { \
  _Pragma("unroll") for (int mt = 0; mt < 4; mt++) \
  _Pragma("unroll") for (int ks = 0; ks < 2; ks++) \
    AF[mt][ks] = *(const bf16x8*)((const char*)Asmem[CUR] + (RBASE) + aoff[mt][ks]); \
} while (0)

#define DS_B2(CUR, N0) do { \
  _Pragma("unroll") for (int nt = 0; nt < 2; nt++) \
  _Pragma("unroll") for (int ks = 0; ks < 2; ks++) \
    bfr[(N0) + nt][ks] = *(const bf16x8*)((const char*)Bsmem[CUR] + boff[(N0) + nt][ks]); \
} while (0)

#define MQ(MB, NB, AF) do { \
  _Pragma("unroll") for (int mt = 0; mt < 4; mt++) \
  _Pragma("unroll") for (int nt = 0; nt < 2; nt++) \
  _Pragma("unroll") for (int ks = 0; ks < 2; ks++) \
    acc[(MB) + mt][(NB) + nt] = MFMA16(AF[mt][ks], bfr[(NB) + nt][ks], acc[(MB) + mt][(NB) + nt]); \
} while (0)

// CA: A-buffer being read (T%3); NA: A-buffer staged into ((T+2)%3);
// CB: B-buffer read AND staged ((T)&1 == (T+2)&1).
#define HALF_ITER(CA, NA, CB, TA, TB, ENDW) do { \
  DS_A(CA, afl, 0); DS_B2(CB, 0); SCHED0(); \
  DS_B2(CB, 2); SCHED0(); \
  DS_A(CA, afh, 8192); SCHED0(); \
  STAGE_A(TA, 0, NA); STAGE_A(TA, 1, NA); \
  LGKM(12); PRIO1(); MQ(0, 0, afl); PRIO0(); \
  LGKM(8);  PRIO1(); MQ(0, 2, afl); PRIO0(); \
  BARR();  /* all waves past lgkm(8) -> every B-read of Bsmem[CB] complete */ \
  STAGE_B(TB, 0, CB); STAGE_B(TB, 1, CB); \
  LGKM(0);  PRIO1(); MQ(4, 0, afh); MQ(4, 2, afh); PRIO0(); \
  ENDW; \
  BARR(); \
} while (0)

template <int EPI>
__global__ __launch_bounds__(512, 2)
void gemm8p(const u16* __restrict__ Ag, const u16* __restrict__ Wg,
            u16* __restrict__ qb, u16* __restrict__ kb, u16* __restrict__ vT,
            const float* __restrict__ bias, float* __restrict__ outf, int nbx)
{
  __shared__ u16 Asmem[3][16384];   // 96KB: triple-buffered A
  __shared__ u16 Bsmem[2][16384];   // 64KB: double-buffered B  (160KB total)

  // row-major XCD-chunked mapping (round-3)
  const int nwg = gridDim.x;            // divisible by 8
  const int cpx = nwg >> 3;
  const int bid = blockIdx.x;
  const int wg  = (bid & 7) * cpx + (bid >> 3);
  const int bx = wg % nbx, by = wg / nbx;
  const int row0 = by * 256, col0 = bx * 256;

  const int t = threadIdx.x;
  const int lane = t & 63, w = t >> 6;
  const int quad = lane >> 4, l16 = lane & 15;
  const int wm = w >> 2, wn = w & 3;   // 2M x 4N waves; per-wave C = 128x64
  const int sx = l16 & 7;

  // stage source (pre-swizzled chunk so LDS stays linear)
  const int srow = lane >> 3;
  const int scol = ((lane & 7) ^ srow) * 8;
  const u16* pA0 = Ag + (size_t)(row0 + w * 16 + srow) * 1024 + scol;
  const u16* pB0 = Wg + (size_t)(col0 + w * 16 + srow) * 1024 + scol;

  // ds_read byte offsets: row r = (wm*128|wn*64) + xt*16 + l16, slot=(ks*4+quad)^(r&7)
  int aoff[4][2], boff[4][2];
#pragma unroll
  for (int mt = 0; mt < 4; mt++)
#pragma unroll
    for (int ks = 0; ks < 2; ks++) {
      int r = wm * 128 + mt * 16 + l16;
      aoff[mt][ks] = r * 128 + (((ks * 4 + quad) ^ sx) * 16);
    }
#pragma unroll
  for (int nt = 0; nt < 4; nt++)
#pragma unroll
    for (int ks = 0; ks < 2; ks++) {
      int r = wn * 64 + nt * 16 + l16;
      boff[nt][ks] = r * 128 + (((ks * 4 + quad) ^ sx) * 16);
    }

  f32x4 acc[8][4];
#pragma unroll
  for (int i = 0; i < 8; i++)
#pragma unroll
    for (int j = 0; j < 4; j++) acc[i][j] = f32x4{0.f, 0.f, 0.f, 0.f};

  auto STAGE_A = [&](int tile, int half, int dst) {
    if (tile >= 16) return;
    const u16* g = pA0 + (size_t)half * 131072 + tile * 64;
    u16* l = &Asmem[dst][(half * 128 + w * 16) * 64];
    gll16(g, l);
    gll16(g + 8192, l + 512);
  };
  auto STAGE_B = [&](int tile, int half, int dst) {
    if (tile >= 16) return;
    const u16* g = pB0 + (size_t)half * 131072 + tile * 64;
    u16* l = &Bsmem[dst][(half * 128 + w * 16) * 64];
    gll16(g, l);
    gll16(g + 8192, l + 512);
  };

  bf16x8 afl[4][2], afh[4][2], bfr[4][2];

  // prologue: B0,A0 (8 loads), then B1,A1 (8); vmcnt(8) -> B0,A0 landed.
  STAGE_B(0, 0, 0); STAGE_B(0, 1, 0); STAGE_A(0, 0, 0); STAGE_A(0, 1, 0);
  SCHED0();
  STAGE_B(1, 0, 1); STAGE_B(1, 1, 1); STAGE_A(1, 0, 1); STAGE_A(1, 1, 1);
  VMC(8); BARR();

  // tiles 0..11: CURA = T%3 (0,1,2,...), CURB = T&1, stage T+2
#pragma unroll 1
  for (int i = 0; i < 2; ++i) {
    int T = 6 * i;
    HALF_ITER(0, 2, 0, T + 2, T + 2, VMC(8));
    HALF_ITER(1, 0, 1, T + 3, T + 3, VMC(8));
    HALF_ITER(2, 1, 0, T + 4, T + 4, VMC(8));
    HALF_ITER(0, 2, 1, T + 5, T + 5, VMC(8));
    HALF_ITER(1, 0, 0, T + 6, T + 6, VMC(8));
    HALF_ITER(2, 1, 1, T + 7, T + 7, VMC(8));
  }
  // tiles 12..15
  HALF_ITER(0, 2, 0, 14, 14, VMC(8));     // T=12: stages 14; A13,B13 landed
  HALF_ITER(1, 0, 1, 15, 15, VMC(8));     // T=13: stages 15; A14,B14 landed
  HALF_ITER(2, 1, 0, 16, 16, VMC(0));     // T=14: no stage; drain A15,B15
  HALF_ITER(0, 2, 1, 17, 17, ((void)0));  // T=15

  const int tok_base = row0 + wm * 128;
  if constexpr (EPI == 0) {
#pragma unroll
    for (int nt = 0; nt < 4; nt++) {
      int d = col0 + wn * 64 + nt * 16;   // tile-uniform
      int part = d >> 10;
      int hh = (d >> 6) & 15;
      int hd = (d & 63) + l16;
      if (part == 2) {
#pragma unroll
        for (int mt = 0; mt < 8; mt++) {
          int nb = tok_base + mt * 16 + quad * 4;   // 4 consecutive tokens
          int bb = nb >> 9, nn = nb & 511;
          uint2 pk;
          pk.x = f2b(acc[mt][nt][0]) | ((unsigned)f2b(acc[mt][nt][1]) << 16);
          pk.y = f2b(acc[mt][nt][2]) | ((unsigned)f2b(acc[mt][nt][3]) << 16);
          *(uint2*)(vT + (((size_t)(bb * 16 + hh)) * 64 + hd) * 512 + nn) = pk;
        }
      } else {
        u16* dst = (part == 0) ? qb : kb;
        float sc = (part == 0) ? 0.125f : 1.0f;
#pragma unroll
        for (int mt = 0; mt < 8; mt++)
#pragma unroll
          for (int r = 0; r < 4; r++) {
            int tok = tok_base + mt * 16 + quad * 4 + r;
            int bb = tok >> 9, nn = tok & 511;
            dst[(((size_t)(bb * 16 + hh)) * 512 + nn) * 64 + hd] = f2b(acc[mt][nt][r] * sc);
          }
      }
    }
  } else {
#pragma unroll
    for (int nt = 0; nt < 4; nt++) {
      int d = col0 + wn * 64 + nt * 16 + l16;
      float bv = bias[d];
#pragma unroll
      for (int mt = 0; mt < 8; mt++)
#pragma unroll
        for (int r = 0; r < 4; r++) {
          int tok = tok_base + mt * 16 + quad * 4 + r;
          outf[(size_t)tok * 1024 + d] = acc[mt][nt][r] + bv;
        }
    }
  }
}

// ------------------------------------------------------------------
// Attention (round-1 verified): 32x32 MFMA, swapped QK^T, lane-local
// softmax (no max-subtract; bounded inputs), in-register P via
// cvt_pk + permlane32_swap, K/V double-buffered via global_load_lds.
// ------------------------------------------------------------------
__global__ __launch_bounds__(256)
void attn_kernel(const u16* __restrict__ qb, const u16* __restrict__ kb,
                 const u16* __restrict__ vT, const float* __restrict__ mask,
                 u16* __restrict__ ao)
{
  __shared__ u16 Kbuf[2][64 * 64];   // [buf][key][d]   rows 128B, swizzled chunks
  __shared__ u16 Vbuf[2][64 * 64];   // [buf][d][key]
  __shared__ float mk2[512];         // mask * log2(e)
  __shared__ float Lbuf[128];        // per-(wave,qrow) 1/l

  const int bid = blockIdx.x;
  const int wid = (bid & 7) * 256 + (bid >> 3);   // XCD-chunked (2048 % 8 == 0)
  const int qt = wid & 3, bh = wid >> 2;
  const int b = bh >> 4, hh = bh & 15;

  const int t = threadIdx.x;
  const int lane = t & 63, w = t >> 6;
  const int l31 = lane & 31, hi = lane >> 5;
  const int sw = l31 & 7;

  const u16* Qp = qb + (size_t)bh * 512 * 64;
  const u16* Kp = kb + (size_t)bh * 512 * 64;
  const u16* Vp = vT + (size_t)bh * 64 * 512;

  for (int i = t; i < 512; i += 256) mk2[i] = mask[b * 512 + i] * 1.44269504f;

  const int qbase = qt * 128 + w * 32;
  bf16x8 qf[4];
#pragma unroll
  for (int dc = 0; dc < 4; dc++)
    qf[dc] = *(const bf16x8*)(Qp + (size_t)(qbase + l31) * 64 + dc * 16 + hi * 8);

  const int sr = lane >> 3, sc = lane & 7;
  const int cg = sc ^ sr;
  const u16* gk[2]; const u16* gv[2];
#pragma unroll
  for (int j = 0; j < 2; j++) {
    int r = w * 16 + j * 8 + sr;
    gk[j] = Kp + (size_t)r * 64 + cg * 8;
    gv[j] = Vp + (size_t)r * 512 + cg * 8;
  }

  f32x16 oacc[2];
#pragma unroll
  for (int i = 0; i < 16; i++) { oacc[0][i] = 0.f; oacc[1][i] = 0.f; }
  float lsum = 0.f;

  auto STAGE = [&](int tt, int buf) {
#pragma unroll
    for (int j = 0; j < 2; j++) {
      gll16(gk[j] + (size_t)tt * 4096, &Kbuf[buf][(w * 16 + j * 8) * 64]);
      gll16(gv[j] + (size_t)tt * 64,   &Vbuf[buf][(w * 16 + j * 8) * 64]);
    }
  };

  STAGE(0, 0);
  __syncthreads();

  for (int tt = 0; tt < 8; tt++) {
    const int cur = tt & 1;
    if (tt < 7) STAGE(tt + 1, cur ^ 1);
    const u16* Kb = Kbuf[cur];
    const u16* Vb = Vbuf[cur];
#pragma unroll
    for (int c = 0; c < 2; c++) {
      f32x16 s;
#pragma unroll
      for (int i = 0; i < 16; i++) s[i] = 0.f;
#pragma unroll
      for (int dc = 0; dc < 4; dc++) {
        int row = c * 32 + l31;
        bf16x8 kf = *(const bf16x8*)((const char*)Kb + row * 128 + (((2 * dc + hi) ^ sw) * 16));
        s = MFMA32(kf, qf[dc], s);
      }
      const int kb0 = tt * 64 + c * 32;
      f32x4 mkv[4];
#pragma unroll
      for (int g = 0; g < 4; g++) mkv[g] = *(const f32x4*)(mk2 + kb0 + g * 8 + hi * 4);
      float p[16];
#pragma unroll
      for (int r = 0; r < 16; r++)
        p[r] = EXP2F(fmaf(s[r], 1.44269504f, mkv[r >> 2][r & 3]));
      float ls = 0.f;
#pragma unroll
      for (int r = 0; r < 16; r++) ls += p[r];
      lsum += ls;

      unsigned d0a = cvtpk(p[0],  p[1]),  d1a = cvtpk(p[2],  p[3]);
      unsigned d2a = cvtpk(p[4],  p[5]),  d3a = cvtpk(p[6],  p[7]);
      unsigned d0b = cvtpk(p[8],  p[9]),  d1b = cvtpk(p[10], p[11]);
      unsigned d2b = cvtpk(p[12], p[13]), d3b = cvtpk(p[14], p[15]);
      pl32swap(d0a, d2a);
      pl32swap(d1a, d3a);
      pl32swap(d0b, d2b);
      pl32swap(d1b, d3b);
      u32x4 w0; w0.x = d0a; w0.y = d1a; w0.z = d2a; w0.w = d3a;
      u32x4 w1; w1.x = d0b; w1.y = d1b; w1.z = d2b; w1.w = d3b;
      bf16x8 af[2];
      af[0] = __builtin_bit_cast(bf16x8, w0);
      af[1] = __builtin_bit_cast(bf16x8, w1);

#pragma unroll
      for (int kc = 0; kc < 2; kc++)
#pragma unroll
        for (int dc = 0; dc < 2; dc++) {
          int row = dc * 32 + l31;
          bf16x8 vf = *(const bf16x8*)((const char*)Vb + row * 128 + (((4 * c + 2 * kc + hi) ^ sw) * 16));
          oacc[dc] = MFMA32(af[kc], vf, oacc[dc]);
        }
    }
    __syncthreads();
  }

  lsum += __shfl_xor(lsum, 32);
  if (lane < 32) Lbuf[w * 32 + l31] = 1.0f / lsum;
  __syncthreads();
  f32x4 inv4[4];
#pragma unroll
  for (int g = 0; g < 4; g++) inv4[g] = *(const f32x4*)(Lbuf + w * 32 + g * 8 + hi * 4);

#pragma unroll
  for (int dc = 0; dc < 2; dc++)
#pragma unroll
    for (int r = 0; r < 16; r++) {
      int qrow = (r & 3) + 8 * (r >> 2) + 4 * hi;
      int n = qbase + qrow;
      int col = hh * 64 + dc * 32 + l31;
      ao[((size_t)(b * 512 + n)) * 1024 + col] = f2b(oacc[dc][r] * inv4[r >> 2][r & 3]);
    }
}

extern "C" void kernel_launch(void* const* d_in, const int* in_sizes, int n_in,
                              void* d_out, int out_size, void* d_ws, size_t ws_size,
                              hipStream_t stream) {
  const float* x     = (const float*)d_in[0];
  const float* mask  = (const float*)d_in[1];
  const float* Wqkv  = (const float*)d_in[2];
  const float* Wproj = (const float*)d_in[3];
  const float* bproj = (const float*)d_in[4];
  float* out = (float*)d_out;

  // ws carve (u16 elems): qb|kb|vT|{Xb then ao}|Wqb|Wpb
  u16* qb  = (u16*)d_ws;
  u16* kb  = qb + 16777216;
  u16* vT  = kb + 16777216;
  u16* XbAo = vT + 16777216;     // Xb during qkv_gemm; ao afterwards (x dead)
  u16* Wqb = XbAo + 16777216;
  u16* Wpb = Wqb + 3145728;

  cvt_all<<<20480, 256, 0, stream>>>(x, Wqkv, Wproj, XbAo, Wqb, Wpb);
  gemm8p<0><<<768, 512, 0, stream>>>(XbAo, Wqb, qb, kb, vT, nullptr, nullptr, 12);
  attn_kernel<<<2048, 256, 0, stream>>>(qb, kb, vT, mask, XbAo);
  gemm8p<1><<<256, 512, 0, stream>>>(XbAo, Wpb, nullptr, nullptr, nullptr, bproj, out, 4);
}

// Round 7
// 326.403 us; speedup vs baseline: 1.1522x; 1.1522x over previous
//
#include <hip/hip_runtime.h>
#include <stdint.h>

typedef unsigned short u16;
typedef __bf16 bf16x8 __attribute__((ext_vector_type(8)));
typedef float  f32x4  __attribute__((ext_vector_type(4)));
typedef float  f32x16 __attribute__((ext_vector_type(16)));
typedef unsigned int u32x4 __attribute__((ext_vector_type(4)));

#define MFMA16(a,b,c) __builtin_amdgcn_mfma_f32_16x16x32_bf16((a),(b),(c),0,0,0)
#define MFMA32(a,b,c) __builtin_amdgcn_mfma_f32_32x32x16_bf16((a),(b),(c),0,0,0)

#if __has_builtin(__builtin_amdgcn_exp2f)
#define EXP2F(x) __builtin_amdgcn_exp2f(x)
#else
#define EXP2F(x) exp2f(x)
#endif

// B=32, N=512, C=1024, H=16, HD=64; SCALE = 1/8
__device__ __forceinline__ u16 f2b(float f) {
  unsigned int u = __builtin_bit_cast(unsigned int, f);
  u += 0x7fffu + ((u >> 16) & 1u);
  return (u16)(u >> 16);
}

// async 16B global->LDS (lds dest wave-uniform; lane i lands at l + i*16)
__device__ __forceinline__ void gll16(const u16* g, u16* l) {
  __builtin_amdgcn_global_load_lds((const __attribute__((address_space(1))) unsigned int*)g,
                                   (__attribute__((address_space(3))) unsigned int*)l,
                                   16, 0, 0);
}

// packed f32x2 -> bf16x2
__device__ __forceinline__ unsigned cvtpk(float lo, float hi) {
  unsigned r;
  asm("v_cvt_pk_bf16_f32 %0, %1, %2" : "=v"(r) : "v"(lo), "v"(hi));
  return r;
}
// swap upper 32 lanes of x with lower 32 lanes of y
__device__ __forceinline__ void pl32swap(unsigned &x, unsigned &y) {
  asm volatile("v_permlane32_swap_b32 %0, %1" : "+v"(x), "+v"(y));
}

#define BARR() __builtin_amdgcn_s_barrier()
#define SCHED0() __builtin_amdgcn_sched_barrier(0)
#define LGKM(N) do { asm volatile("s_waitcnt lgkmcnt(" #N ")" ::: "memory"); __builtin_amdgcn_sched_barrier(0); } while (0)
#define VMC(N) do { asm volatile("s_waitcnt vmcnt(" #N ")" ::: "memory"); __builtin_amdgcn_sched_barrier(0); } while (0)
#define PRIO1() __builtin_amdgcn_s_setprio(1)
#define PRIO0() __builtin_amdgcn_s_setprio(0)

// ------------------------------------------------------------------
// cvt_all: fp32 -> bf16 for x (16.78M), W_qkv (3.15M), W_proj (1.05M)
// ------------------------------------------------------------------
__global__ __launch_bounds__(256)
void cvt_all(const float* __restrict__ X, const float* __restrict__ Wq,
             const float* __restrict__ Wp, u16* __restrict__ Xb,
             u16* __restrict__ Wqb, u16* __restrict__ Wpb)
{
  size_t i = (size_t)blockIdx.x * 256 + threadIdx.x;   // float4 index
  const float* src; u16* dst; size_t off;
  if (i < 4194304)       { src = X;  dst = Xb;  off = i; }
  else if (i < 4980736)  { src = Wq; dst = Wqb; off = i - 4194304; }
  else                   { src = Wp; dst = Wpb; off = i - 4980736; }
  float4 v = ((const float4*)src)[off];
  uint2 p;
  p.x = f2b(v.x) | ((unsigned)f2b(v.y) << 16);
  p.y = f2b(v.z) | ((unsigned)f2b(v.w) << 16);
  ((uint2*)dst)[off] = p;
}

// ------------------------------------------------------------------
// gemm8p: ROUND-3 EXACT (proven best: qkv ~119us). 256x256 tile, BK=64,
// 8 waves (2Mx4N), counted-lgkm schedule, 2 barriers + 1 full drain
// per K-tile, vmcnt(4) steady / vmcnt(0) at tile 14. Row-major
// XCD-chunked grid mapping. LDS swizzle slot = chunk ^ (row&7) both
// sides (rule 21).
// ------------------------------------------------------------------
#define DS_A(CUR, AF, RBASE) do { \
  _Pragma("unroll") for (int mt = 0; mt < 4; mt++) \
  _Pragma("unroll") for (int ks = 0; ks < 2; ks++) \
    AF[mt][ks] = *(const bf16x8*)((const char*)Asmem[CUR] + (RBASE) + aoff[mt][ks]); \
} while (0)

#define DS_B2(CUR, N0) do { \
  _Pragma("unroll") for (int nt = 0; nt < 2; nt++) \
  _Pragma("unroll") for (int ks = 0; ks < 2; ks++) \
    bfr[(N0) + nt][ks] = *(const bf16x8*)((const char*)Bsmem[CUR] + boff[(N0) + nt][ks]); \
} while (0)

#define MQ(MB, NB, AF) do { \
  _Pragma("unroll") for (int mt = 0; mt < 4; mt++) \
  _Pragma("unroll") for (int nt = 0; nt < 2; nt++) \
  _Pragma("unroll") for (int ks = 0; ks < 2; ks++) \
    acc[(MB) + mt][(NB) + nt] = MFMA16(AF[mt][ks], bfr[(NB) + nt][ks], acc[(MB) + mt][(NB) + nt]); \
} while (0)

#define HALF_ITER(CUR, TA, TB, ENDW) do { \
  DS_A(CUR, afl, 0); DS_B2(CUR, 0); SCHED0(); \
  DS_B2(CUR, 2); SCHED0(); \
  DS_A(CUR, afh, 8192); SCHED0(); \
  STAGE_A(TA, 0); STAGE_A(TA, 1); \
  LGKM(12); PRIO1(); MQ(0, 0, afl); PRIO0(); \
  LGKM(8);  PRIO1(); MQ(0, 2, afl); PRIO0(); \
  BARR();  /* all waves past lgkm(8) -> every B-read of buf[CUR] complete */ \
  STAGE_B(TB, 0); STAGE_B(TB, 1); \
  LGKM(0);  PRIO1(); MQ(4, 0, afh); MQ(4, 2, afh); PRIO0(); \
  ENDW; \
  BARR(); \
} while (0)

template <int EPI>
__global__ __launch_bounds__(512, 2)
void gemm8p(const u16* __restrict__ Ag, const u16* __restrict__ Wg,
            u16* __restrict__ qb, u16* __restrict__ kb, u16* __restrict__ vT,
            const float* __restrict__ bias, float* __restrict__ outf, int nbx)
{
  __shared__ u16 Asmem[2][16384];   // [buf][256r x 64k], row 128B, swizzled slots
  __shared__ u16 Bsmem[2][16384];

  const int nwg = gridDim.x;            // divisible by 8
  const int cpx = nwg >> 3;
  const int bid = blockIdx.x;
  const int wg  = (bid & 7) * cpx + (bid >> 3);   // XCD-chunked (bijective)
  const int bx = wg % nbx, by = wg / nbx;
  const int row0 = by * 256, col0 = bx * 256;

  const int t = threadIdx.x;
  const int lane = t & 63, w = t >> 6;
  const int quad = lane >> 4, l16 = lane & 15;
  const int wm = w >> 2, wn = w & 3;   // 2M x 4N waves; per-wave C = 128x64
  const int sx = l16 & 7;

  const int srow = lane >> 3;
  const int scol = ((lane & 7) ^ srow) * 8;
  const u16* pA0 = Ag + (size_t)(row0 + w * 16 + srow) * 1024 + scol;
  const u16* pB0 = Wg + (size_t)(col0 + w * 16 + srow) * 1024 + scol;

  int aoff[4][2], boff[4][2];
#pragma unroll
  for (int mt = 0; mt < 4; mt++)
#pragma unroll
    for (int ks = 0; ks < 2; ks++) {
      int r = wm * 128 + mt * 16 + l16;
      aoff[mt][ks] = r * 128 + (((ks * 4 + quad) ^ sx) * 16);
    }
#pragma unroll
  for (int nt = 0; nt < 4; nt++)
#pragma unroll
    for (int ks = 0; ks < 2; ks++) {
      int r = wn * 64 + nt * 16 + l16;
      boff[nt][ks] = r * 128 + (((ks * 4 + quad) ^ sx) * 16);
    }

  f32x4 acc[8][4];
#pragma unroll
  for (int i = 0; i < 8; i++)
#pragma unroll
    for (int j = 0; j < 4; j++) acc[i][j] = f32x4{0.f, 0.f, 0.f, 0.f};

  auto STAGE_A = [&](int tile, int half) {
    if (tile >= 16) return;
    const u16* g = pA0 + (size_t)half * 131072 + tile * 64;
    u16* l = &Asmem[tile & 1][(half * 128 + w * 16) * 64];
    gll16(g, l);
    gll16(g + 8192, l + 512);
  };
  auto STAGE_B = [&](int tile, int half) {
    if (tile >= 16) return;
    const u16* g = pB0 + (size_t)half * 131072 + tile * 64;
    u16* l = &Bsmem[tile & 1][(half * 128 + w * 16) * 64];
    gll16(g, l);
    gll16(g + 8192, l + 512);
  };

  bf16x8 afl[4][2], afh[4][2], bfr[4][2];

  STAGE_B(0, 0); STAGE_B(0, 1); STAGE_A(0, 0); STAGE_A(0, 1);
  SCHED0();
  STAGE_B(1, 0); STAGE_B(1, 1);
  VMC(4); BARR();

#pragma unroll 1
  for (int i = 0; i < 7; ++i) {
    int t1 = 2 * i + 1;
    HALF_ITER(0, t1, t1 + 1, VMC(4));
    HALF_ITER(1, t1 + 1, t1 + 2, VMC(4));
  }
  HALF_ITER(0, 15, 16, VMC(0));
  HALF_ITER(1, 16, 17, ((void)0));

  const int tok_base = row0 + wm * 128;
  if constexpr (EPI == 0) {
#pragma unroll
    for (int nt = 0; nt < 4; nt++) {
      int d = col0 + wn * 64 + nt * 16;   // tile-uniform
      int part = d >> 10;
      int hh = (d >> 6) & 15;
      int hd = (d & 63) + l16;
      if (part == 2) {
#pragma unroll
        for (int mt = 0; mt < 8; mt++) {
          int nb = tok_base + mt * 16 + quad * 4;   // 4 consecutive tokens
          int bb = nb >> 9, nn = nb & 511;
          uint2 pk;
          pk.x = f2b(acc[mt][nt][0]) | ((unsigned)f2b(acc[mt][nt][1]) << 16);
          pk.y = f2b(acc[mt][nt][2]) | ((unsigned)f2b(acc[mt][nt][3]) << 16);
          *(uint2*)(vT + (((size_t)(bb * 16 + hh)) * 64 + hd) * 512 + nn) = pk;
        }
      } else {
        u16* dst = (part == 0) ? qb : kb;
        float sc = (part == 0) ? 0.125f : 1.0f;
#pragma unroll
        for (int mt = 0; mt < 8; mt++)
#pragma unroll
          for (int r = 0; r < 4; r++) {
            int tok = tok_base + mt * 16 + quad * 4 + r;
            int bb = tok >> 9, nn = tok & 511;
            dst[(((size_t)(bb * 16 + hh)) * 512 + nn) * 64 + hd] = f2b(acc[mt][nt][r] * sc);
          }
      }
    }
  } else {
#pragma unroll
    for (int nt = 0; nt < 4; nt++) {
      int d = col0 + wn * 64 + nt * 16 + l16;
      float bv = bias[d];
#pragma unroll
      for (int mt = 0; mt < 8; mt++)
#pragma unroll
        for (int r = 0; r < 4; r++) {
          int tok = tok_base + mt * 16 + quad * 4 + r;
          outf[(size_t)tok * 1024 + d] = acc[mt][nt][r] + bv;
        }
    }
  }
}

// ------------------------------------------------------------------
// Attention v3 (round 7): 64 q-rows per wave (2 groups of 32 sharing
// each kf/vf register load) -> LDS-read amplification halved (theory:
// attn is ds_read_b128-port bound, ~41us of ~79us). 256 q-rows/block,
// grid 1024 (2 blocks per bh) -> K/V staging traffic also halved.
// Same verified layout/swizzle math as round-1; launch_bounds(256,2)
// pins VGPR<=256 (est ~200), 2 waves/SIMD.
// ------------------------------------------------------------------
__global__ __launch_bounds__(256, 2)
void attn_kernel(const u16* __restrict__ qb, const u16* __restrict__ kb,
                 const u16* __restrict__ vT, const float* __restrict__ mask,
                 u16* __restrict__ ao)
{
  __shared__ u16 Kbuf[2][64 * 64];   // [buf][key][d]   rows 128B, swizzled chunks
  __shared__ u16 Vbuf[2][64 * 64];   // [buf][d][key]
  __shared__ float mk2[512];         // mask * log2(e)
  __shared__ float Lbuf[256];        // per-(wave,group,qrow) 1/l

  const int bid = blockIdx.x;
  const int wid = (bid & 7) * 128 + (bid >> 3);   // XCD-chunked (1024 % 8 == 0)
  const int qt = wid & 1, bh = wid >> 1;          // 2 q-halves per bh, same XCD
  const int b = bh >> 4, hh = bh & 15;

  const int t = threadIdx.x;
  const int lane = t & 63, w = t >> 6;
  const int l31 = lane & 31, hi = lane >> 5;
  const int sw = l31 & 7;

  const u16* Qp = qb + (size_t)bh * 512 * 64;
  const u16* Kp = kb + (size_t)bh * 512 * 64;
  const u16* Vp = vT + (size_t)bh * 64 * 512;

  for (int i = t; i < 512; i += 256) mk2[i] = mask[b * 512 + i] * 1.44269504f;

  // wave handles q-rows [qbase, qbase+64): two 32-row groups
  const int qbase = qt * 256 + w * 64;
  bf16x8 qf[2][4];
#pragma unroll
  for (int g = 0; g < 2; g++)
#pragma unroll
    for (int dc = 0; dc < 4; dc++)
      qf[g][dc] = *(const bf16x8*)(Qp + (size_t)(qbase + g * 32 + l31) * 64 + dc * 16 + hi * 8);

  const int sr = lane >> 3, sc = lane & 7;
  const int cg = sc ^ sr;
  const u16* gk[2]; const u16* gv[2];
#pragma unroll
  for (int j = 0; j < 2; j++) {
    int r = w * 16 + j * 8 + sr;
    gk[j] = Kp + (size_t)r * 64 + cg * 8;
    gv[j] = Vp + (size_t)r * 512 + cg * 8;
  }

  f32x16 oacc[2][2];
#pragma unroll
  for (int g = 0; g < 2; g++)
#pragma unroll
    for (int i = 0; i < 16; i++) { oacc[g][0][i] = 0.f; oacc[g][1][i] = 0.f; }
  float lsum[2] = {0.f, 0.f};

  auto STAGE = [&](int tt, int buf) {
#pragma unroll
    for (int j = 0; j < 2; j++) {
      gll16(gk[j] + (size_t)tt * 4096, &Kbuf[buf][(w * 16 + j * 8) * 64]);
      gll16(gv[j] + (size_t)tt * 64,   &Vbuf[buf][(w * 16 + j * 8) * 64]);
    }
  };

  STAGE(0, 0);
  __syncthreads();

  for (int tt = 0; tt < 8; tt++) {
    const int cur = tt & 1;
    if (tt < 7) STAGE(tt + 1, cur ^ 1);
    const u16* Kb = Kbuf[cur];
    const u16* Vb = Vbuf[cur];
#pragma unroll
    for (int c = 0; c < 2; c++) {
      // QK^T for both groups sharing each kf load
      f32x16 s[2];
#pragma unroll
      for (int g = 0; g < 2; g++)
#pragma unroll
        for (int i = 0; i < 16; i++) s[g][i] = 0.f;
#pragma unroll
      for (int dc = 0; dc < 4; dc++) {
        int row = c * 32 + l31;
        bf16x8 kf = *(const bf16x8*)((const char*)Kb + row * 128 + (((2 * dc + hi) ^ sw) * 16));
        s[0] = MFMA32(kf, qf[0][dc], s[0]);
        s[1] = MFMA32(kf, qf[1][dc], s[1]);
      }
      const int kb0 = tt * 64 + c * 32;
      f32x4 mkv[4];
#pragma unroll
      for (int gg = 0; gg < 4; gg++) mkv[gg] = *(const f32x4*)(mk2 + kb0 + gg * 8 + hi * 4);

      bf16x8 af[2][2];
#pragma unroll
      for (int g = 0; g < 2; g++) {
        float p[16];
#pragma unroll
        for (int r = 0; r < 16; r++)
          p[r] = EXP2F(fmaf(s[g][r], 1.44269504f, mkv[r >> 2][r & 3]));
        float ls = 0.f;
#pragma unroll
        for (int r = 0; r < 16; r++) ls += p[r];
        lsum[g] += ls;

        unsigned d0a = cvtpk(p[0],  p[1]),  d1a = cvtpk(p[2],  p[3]);
        unsigned d2a = cvtpk(p[4],  p[5]),  d3a = cvtpk(p[6],  p[7]);
        unsigned d0b = cvtpk(p[8],  p[9]),  d1b = cvtpk(p[10], p[11]);
        unsigned d2b = cvtpk(p[12], p[13]), d3b = cvtpk(p[14], p[15]);
        pl32swap(d0a, d2a);
        pl32swap(d1a, d3a);
        pl32swap(d0b, d2b);
        pl32swap(d1b, d3b);
        u32x4 w0; w0.x = d0a; w0.y = d1a; w0.z = d2a; w0.w = d3a;
        u32x4 w1; w1.x = d0b; w1.y = d1b; w1.z = d2b; w1.w = d3b;
        af[g][0] = __builtin_bit_cast(bf16x8, w0);
        af[g][1] = __builtin_bit_cast(bf16x8, w1);
      }

      // PV: both groups share each vf load
#pragma unroll
      for (int kc = 0; kc < 2; kc++)
#pragma unroll
        for (int dc = 0; dc < 2; dc++) {
          int row = dc * 32 + l31;
          bf16x8 vf = *(const bf16x8*)((const char*)Vb + row * 128 + (((4 * c + 2 * kc + hi) ^ sw) * 16));
          oacc[0][dc] = MFMA32(af[0][kc], vf, oacc[0][dc]);
          oacc[1][dc] = MFMA32(af[1][kc], vf, oacc[1][dc]);
        }
    }
    __syncthreads();
  }

#pragma unroll
  for (int g = 0; g < 2; g++) {
    lsum[g] += __shfl_xor(lsum[g], 32);
    if (lane < 32) Lbuf[w * 64 + g * 32 + l31] = 1.0f / lsum[g];
  }
  __syncthreads();
  f32x4 inv4[2][4];
#pragma unroll
  for (int g = 0; g < 2; g++)
#pragma unroll
    for (int gg = 0; gg < 4; gg++)
      inv4[g][gg] = *(const f32x4*)(Lbuf + w * 64 + g * 32 + gg * 8 + hi * 4);

#pragma unroll
  for (int g = 0; g < 2; g++)
#pragma unroll
    for (int dc = 0; dc < 2; dc++)
#pragma unroll
      for (int r = 0; r < 16; r++) {
        int qrow = (r & 3) + 8 * (r >> 2) + 4 * hi;
        int n = qbase + g * 32 + qrow;
        int col = hh * 64 + dc * 32 + l31;
        ao[((size_t)(b * 512 + n)) * 1024 + col] = f2b(oacc[g][dc][r] * inv4[g][r >> 2][r & 3]);
      }
}

extern "C" void kernel_launch(void* const* d_in, const int* in_sizes, int n_in,
                              void* d_out, int out_size, void* d_ws, size_t ws_size,
                              hipStream_t stream) {
  const float* x     = (const float*)d_in[0];
  const float* mask  = (const float*)d_in[1];
  const float* Wqkv  = (const float*)d_in[2];
  const float* Wproj = (const float*)d_in[3];
  const float* bproj = (const float*)d_in[4];
  float* out = (float*)d_out;

  // ws carve (u16 elems): qb|kb|vT|{Xb then ao}|Wqb|Wpb
  u16* qb  = (u16*)d_ws;
  u16* kb  = qb + 16777216;
  u16* vT  = kb + 16777216;
  u16* XbAo = vT + 16777216;     // Xb during qkv_gemm; ao afterwards (x dead)
  u16* Wqb = XbAo + 16777216;
  u16* Wpb = Wqb + 3145728;

  cvt_all<<<20480, 256, 0, stream>>>(x, Wqkv, Wproj, XbAo, Wqb, Wpb);
  gemm8p<0><<<768, 512, 0, stream>>>(XbAo, Wqb, qb, kb, vT, nullptr, nullptr, 12);
  attn_kernel<<<1024, 256, 0, stream>>>(qb, kb, vT, mask, XbAo);
  gemm8p<1><<<256, 512, 0, stream>>>(XbAo, Wpb, nullptr, nullptr, nullptr, bproj, out, 4);
}